// Round 10
// baseline (231.827 us; speedup 1.0000x reference)
//
#include <hip/hip_runtime.h>
#include <cstddef>
#include <cstdint>

#define N_BATCH 32
#define WIDTH   512
#define T_DIM   2048
#define NB_CODE 1024
#define M_ROWS  65536
#define OUT_ELEMS 33554432
#define IDX_OFF  OUT_ELEMS
#define LOSS_OFF (OUT_ELEMS + M_ROWS)
#define PERP_OFF (LOSS_OFF + 1)
#define MARGIN   0.75f

typedef __attribute__((ext_vector_type(8))) short vshort8;
typedef __attribute__((ext_vector_type(4))) float vfloat4;
typedef __attribute__((ext_vector_type(16))) float vfloat16;

typedef __attribute__((address_space(1))) const uint32_t gu32_t;
typedef __attribute__((address_space(3))) uint32_t lu32_t;
static __device__ __forceinline__ void gload16(const void* g, void* l) {
    __builtin_amdgcn_global_load_lds((gu32_t*)g, (lu32_t*)l, 16, 0, 0);
}

static __device__ __forceinline__ unsigned short f2bf(float f) {
    uint32_t u = __float_as_uint(f);
    uint32_t r = (u + 0x7FFFu + ((u >> 16) & 1u)) >> 16;  // RNE
    return (unsigned short)r;
}
static __device__ __forceinline__ float bf2f(unsigned short s) {
    return __uint_as_float(((uint32_t)s) << 16);
}

// ---------------- workspace layout (bytes) ----------------
// cbh 1MB | cnorm 4K | hist 4K | cand 256K | idx 256K | sbest 256K | xnorm 256K

// bf16 codebook + per-code norms + hist zeroing.
__global__ __launch_bounds__(128) void k_prep(const float* __restrict__ cb,
                                              unsigned short* __restrict__ cbh,
                                              float* __restrict__ cnorm,
                                              int* __restrict__ hist) {
    const int c = blockIdx.x, tid = threadIdx.x;
    float4 v = ((const float4*)(cb + (size_t)c * WIDTH))[tid];
    ushort4 h;
    h.x = f2bf(v.x); h.y = f2bf(v.y); h.z = f2bf(v.z); h.w = f2bf(v.w);
    ((ushort4*)(cbh + (size_t)c * WIDTH))[tid] = h;
    float s = v.x * v.x + v.y * v.y + v.z * v.z + v.w * v.w;
#pragma unroll
    for (int off = 32; off >= 1; off >>= 1) s += __shfl_xor(s, off, 64);
    __shared__ float sw[2];
    if ((tid & 63) == 0) sw[tid >> 6] = s;
    __syncthreads();
    if (tid == 0) { cnorm[c] = sw[0] + sw[1]; hist[c] = 0; }
}

// hh-screen argmin, 32x32x16 MFMA, fused x load/convert.
// 512 blocks x 256 thr (4 waves), 128 rows/block, 32 rows/wave.
// Codebook chunk = 64 codes x 256 k (32KB), double-buffered -> 68KB LDS
// -> TWO independent blocks/CU (separate barrier domains overlap stalls).
// 32 phases; acc persists across the 2 k-half phases of each code-chunk.
__global__ __launch_bounds__(256) void k_argmin(
    const float* __restrict__ x, const unsigned short* __restrict__ cbh,
    const float* __restrict__ cnorm, uint32_t* __restrict__ cand,
    float* __restrict__ sbest, float* __restrict__ xnorm) {
    __shared__ __align__(16) short lds[2][16384];   // 2 x 32KB
    __shared__ __align__(16) float cns[NB_CODE];

    const int tid = threadIdx.x;
    const int wv = tid >> 6, l = tid & 63;
    const int l31 = l & 31, hi = l >> 5;

    // staging source offsets (inverse swizzle). Tile = 64 codes x 256 k:
    // LDS byte = kq*16384 + code*256 + (slot^(code&15))*16, kq=k/128, slot=(k%128)/8
    int srcoff[8];
#pragma unroll
    for (int j = 0; j < 8; ++j) {
        const int q = j * 256 + tid;                 // 16B slot index 0..2047
        const int kq = q >> 10, code = (q >> 4) & 63, sx = q & 15;
        const int slot = sx ^ (code & 15);
        srcoff[j] = code * 1024 + kq * 256 + slot * 16;
    }

#define STAGE(SP, B) do {                                                     \
    const char* cbbase_ = ((const char*)cbh) + ((SP) >> 1) * 65536 + ((SP) & 1) * 512; \
    short* lb_ = &lds[B][0];                                                  \
    _Pragma("unroll")                                                         \
    for (int j = 0; j < 8; ++j)                                               \
        gload16(cbbase_ + srcoff[j], lb_ + (j * 256 + tid) * 8);              \
} while (0)

    STAGE(0, 0);

    { ((float4*)cns)[tid] = ((const float4*)cnorm)[tid]; }

    // ---- fused x load: 32 rows/wave, coalesced f32 (lane=t), cvt_pk to bf16.
    const int m0w = blockIdx.x * 128 + wv * 32;
    const int n = m0w >> 11;
    const int tcol = (m0w & 2047) + l31;
    vshort8 xh[32];
    float xn = 0.f;
    {
        const float* xb = x + (size_t)n * WIDTH * T_DIM + (size_t)hi * 8 * T_DIM + tcol;
        union U8 { uint32_t u[4]; vshort8 v; };
#pragma unroll
        for (int ks = 0; ks < 32; ++ks) {
            U8 u;
#pragma unroll
            for (int j = 0; j < 4; ++j) {
                const float f0 = xb[(size_t)(ks * 16 + 2 * j) * T_DIM];
                const float f1 = xb[(size_t)(ks * 16 + 2 * j + 1) * T_DIM];
                xn = fmaf(f0, f0, fmaf(f1, f1, xn));
                asm("v_cvt_pk_bf16_f32 %0, %1, %2" : "=v"(u.u[j]) : "v"(f0), "v"(f1));
            }
            xh[ks] = u.v;
        }
    }
    xn += __shfl_xor(xn, 32, 64);
    if (l < 32) xnorm[m0w + l] = xn;   // exact fp32 row norm

    const int sxl = l31 & 15;          // read-swizzle XOR source

    float b1 = 3.4e38f, b2 = 3.4e38f, b3 = 3.4e38f;
    int i1 = 0, i2 = 0, i3 = 0;

#define INS3(S, C) do {                                                       \
        const bool lt1 = (S) < b1, lt2 = (S) < b2, lt3 = (S) < b3;            \
        b3 = lt3 ? (lt2 ? b2 : (S)) : b3;  i3 = lt3 ? (lt2 ? i2 : (C)) : i3; \
        b2 = lt2 ? (lt1 ? b1 : (S)) : b2;  i2 = lt2 ? (lt1 ? i1 : (C)) : i2; \
        b1 = lt1 ? (S) : b1;               i1 = lt1 ? (C) : i1;              \
    } while (0)

    __syncthreads();   // full drain: chunk0, cns, x loads

    for (int cc = 0; cc < 16; ++cc) {
        vfloat16 acc0 = {}, acc1 = {};
#pragma unroll
        for (int kh = 0; kh < 2; ++kh) {
            const int sp = cc * 2 + kh;
            if (sp) {
                asm volatile("s_waitcnt vmcnt(0)" ::: "memory");  // own STAGE(sp) done
                __builtin_amdgcn_s_barrier();                     // everyone's done
            }
            if (sp < 31) {
                if (sp & 1) STAGE(sp + 1, 0); else STAGE(sp + 1, 1);
            }
            const short* buf = lds[sp & 1];
            __builtin_amdgcn_s_setprio(1);
#pragma unroll
            for (int ks = 0; ks < 16; ++ks) {
                // k_local = ks*16 + hi*8; kq=ks>>3, slot=((ks&7)<<1)|hi
                const int addr0 = (ks >> 3) * 8192 + l31 * 128 +
                                  (((((ks & 7) << 1) | hi) ^ sxl) << 3);
                vshort8 a0 = *(const vshort8*)&buf[addr0];
                acc0 = __builtin_amdgcn_mfma_f32_32x32x16_bf16(a0, xh[kh * 16 + ks], acc0, 0, 0, 0);
                vshort8 a1 = *(const vshort8*)&buf[addr0 + 4096];
                acc1 = __builtin_amdgcn_mfma_f32_32x32x16_bf16(a1, xh[kh * 16 + ks], acc1, 0, 0, 0);
            }
            __builtin_amdgcn_s_setprio(0);
        }
        // score 64 codes: D[code][row], col=lane&31=row, code=(r&3)+8*(r>>2)+4*hi
        const int cb0 = cc * 64;
#pragma unroll
        for (int tl = 0; tl < 2; ++tl) {
#pragma unroll
            for (int g = 0; g < 4; ++g) {
                const int cbase = cb0 + tl * 32 + g * 8 + 4 * hi;
                vfloat4 cn = *(const vfloat4*)&cns[cbase];
#pragma unroll
                for (int j = 0; j < 4; ++j) {
                    const float a = tl ? acc1[g * 4 + j] : acc0[g * 4 + j];
                    const float s = fmaf(-2.f, a, cn[j]);
                    INS3(s, cbase + j);
                }
            }
        }
    }

    // merge top-3 across the hi halves (disjoint code sets)
    {
        const float ob1 = __shfl_xor(b1, 32, 64), ob2 = __shfl_xor(b2, 32, 64), ob3 = __shfl_xor(b3, 32, 64);
        const int oi1 = __shfl_xor(i1, 32, 64), oi2 = __shfl_xor(i2, 32, 64), oi3 = __shfl_xor(i3, 32, 64);
        INS3(ob1, oi1); INS3(ob2, oi2); INS3(ob3, oi3);
    }
    if (l < 32) {
        const uint32_t f2 = (b2 - b1 < MARGIN) ? 1u : 0u;
        const uint32_t f3 = (b3 - b1 < MARGIN) ? 1u : 0u;
        cand[m0w + l] = (uint32_t)i1 | ((uint32_t)i2 << 10) | ((uint32_t)i3 << 20) | (f2 << 30) | (f3 << 31);
        sbest[m0w + l] = b1;   // screen-score of winner (overwritten if rescored)
    }
}

// EXACT fp32 rescore of flagged rows (original x + fp32 cb), one wave/row.
// Writes final idx + exact winning score.
__global__ __launch_bounds__(256) void k_rescore(
    const float* __restrict__ x, const float* __restrict__ cb,
    const float* __restrict__ cnorm, const uint32_t* __restrict__ cand,
    int* __restrict__ idx_final, float* __restrict__ sbest) {
    __shared__ int list[64];
    __shared__ int cnt;
    const int tid = threadIdx.x;
    const int m0 = blockIdx.x * 64;
    if (tid == 0) cnt = 0;
    __syncthreads();
    if (tid < 64) {
        const uint32_t wv = cand[m0 + tid];
        if (wv >> 30) { const int p = atomicAdd(&cnt, 1); list[p] = tid; }
        else idx_final[m0 + tid] = (int)(wv & 1023u);
    }
    __syncthreads();
    const int nf = cnt;
    const int w = tid >> 6, lid = tid & 63;
    for (int it = w; it < nf; it += 4) {
        const int row = m0 + list[it];
        const uint32_t wv = cand[row];
        const int j1 = (int)(wv & 1023u), j2 = (int)((wv >> 10) & 1023u), j3 = (int)((wv >> 20) & 1023u);
        const bool nd3 = (wv >> 31) & 1u;
        const int n = row >> 11, t = row & 2047;
        const float* xc = x + (size_t)n * WIDTH * T_DIM + t;
        float xv[8];
#pragma unroll
        for (int e = 0; e < 8; ++e)
            xv[e] = xc[(size_t)(lid * 8 + e) * T_DIM];
        float d1 = 0.f, d2 = 0.f, d3 = 0.f;
        {
            const float* c1 = cb + (size_t)j1 * WIDTH + lid * 8;
            const float* c2 = cb + (size_t)j2 * WIDTH + lid * 8;
            const float* c3 = cb + (size_t)j3 * WIDTH + lid * 8;
            float4 a0 = *(const float4*)c1, a1 = *(const float4*)(c1 + 4);
            d1 = fmaf(xv[0], a0.x, fmaf(xv[1], a0.y, fmaf(xv[2], a0.z, fmaf(xv[3], a0.w,
                 fmaf(xv[4], a1.x, fmaf(xv[5], a1.y, fmaf(xv[6], a1.z, xv[7] * a1.w)))))));
            float4 b0 = *(const float4*)c2, b1v = *(const float4*)(c2 + 4);
            d2 = fmaf(xv[0], b0.x, fmaf(xv[1], b0.y, fmaf(xv[2], b0.z, fmaf(xv[3], b0.w,
                 fmaf(xv[4], b1v.x, fmaf(xv[5], b1v.y, fmaf(xv[6], b1v.z, xv[7] * b1v.w)))))));
            if (nd3) {
                float4 g0 = *(const float4*)c3, g1 = *(const float4*)(c3 + 4);
                d3 = fmaf(xv[0], g0.x, fmaf(xv[1], g0.y, fmaf(xv[2], g0.z, fmaf(xv[3], g0.w,
                     fmaf(xv[4], g1.x, fmaf(xv[5], g1.y, fmaf(xv[6], g1.z, xv[7] * g1.w)))))));
            }
        }
#pragma unroll
        for (int off = 32; off >= 1; off >>= 1) {
            d1 += __shfl_xor(d1, off, 64);
            d2 += __shfl_xor(d2, off, 64);
            d3 += __shfl_xor(d3, off, 64);
        }
        if (lid == 0) {
            int win = j1;
            float qw = fmaf(-2.f, d1, cnorm[j1]);
            const float q2 = fmaf(-2.f, d2, cnorm[j2]);
            if (q2 < qw || (q2 == qw && j2 < win)) { win = j2; qw = q2; }
            if (nd3) {
                const float q3 = fmaf(-2.f, d3, cnorm[j3]);
                if (q3 < qw || (q3 == qw && j3 < win)) { win = j3; qw = q3; }
            }
            idx_final[row] = win;
            sbest[row] = qw;
        }
    }
}

// Gather codebook[idx] -> out [N][W][T] via LDS transpose staging,
// idx as float, histogram. (No x reads -- loss comes from the dist identity.)
__global__ __launch_bounds__(256) void k_scatter(
    const float* __restrict__ cb, const int* __restrict__ idx,
    float* __restrict__ dout, int* __restrict__ hist) {
    __shared__ int sidx[64];
    __shared__ float tile[64][130];
    const int tid = threadIdx.x;
    const int b = blockIdx.x;
    const int n = b >> 5;
    const int t0 = (b & 31) * 64;
    if (tid < 64) {
        const int m2 = n * T_DIM + t0 + tid;
        const int ii = idx[m2];
        sidx[tid] = ii;
        dout[IDX_OFF + m2] = (float)ii;
        atomicAdd(&hist[ii], 1);
    }
    __syncthreads();
    const int w = tid >> 6, l = tid & 63;
    for (int wc = 0; wc < 4; ++wc) {
#pragma unroll
        for (int rr = 0; rr < 16; ++rr) {
            const int row = w * 16 + rr;
            const float2 v = *(const float2*)(cb + (size_t)sidx[row] * WIDTH + wc * 128 + l * 2);
            *(float2*)&tile[row][l * 2] = v;
        }
        __syncthreads();
#pragma unroll 8
        for (int wwi = 0; wwi < 32; ++wwi) {
            const int ww = wc * 128 + w * 32 + wwi;
            dout[((size_t)n * WIDTH + ww) * T_DIM + t0 + l] = tile[l][w * 32 + wwi];
        }
        __syncthreads();
    }
}

// perplexity from hist + commit loss = sum(xnorm + s_win) / OUT_ELEMS
__global__ __launch_bounds__(1024) void k_finalize(
    const int* __restrict__ hist, const float* __restrict__ xnorm,
    const float* __restrict__ sbest, float* __restrict__ dout) {
    const int tid = threadIdx.x;
    float e;
    {
        const float p = (float)hist[tid] * (1.0f / (float)M_ROWS);
        e = p * logf(p + 1e-7f);
    }
    float ls = 0.f;
    for (int i = tid; i < M_ROWS; i += 1024) ls += xnorm[i] + sbest[i];
#pragma unroll
    for (int off = 32; off >= 1; off >>= 1) {
        e += __shfl_xor(e, off, 64);
        ls += __shfl_xor(ls, off, 64);
    }
    __shared__ float se[16], sl[16];
    if ((tid & 63) == 0) { se[tid >> 6] = e; sl[tid >> 6] = ls; }
    __syncthreads();
    if (tid == 0) {
        float E = 0.f, L = 0.f;
#pragma unroll
        for (int i = 0; i < 16; ++i) { E += se[i]; L += sl[i]; }
        dout[LOSS_OFF] = L / (float)OUT_ELEMS;
        dout[PERP_OFF] = expf(-E);
    }
}

extern "C" void kernel_launch(void* const* d_in, const int* in_sizes, int n_in,
                              void* d_out, int out_size, void* d_ws, size_t ws_size,
                              hipStream_t stream) {
    const float* x = (const float*)d_in[0];
    const float* cb = (const float*)d_in[1];
    float* dout = (float*)d_out;
    uint8_t* w = (uint8_t*)d_ws;

    unsigned short* cbh = (unsigned short*)w;                        // 1 MB
    float* cnorm   = (float*)(w + (1u << 20));                       // 4 KB
    int*   hist    = (int*)(w + (1u << 20) + 4096);                  // 4 KB
    uint32_t* cand = (uint32_t*)(w + (1u << 20) + 8192);             // 256 KB
    int* idx_final = (int*)(w + (1u << 20) + 8192 + 262144);         // 256 KB
    float* sbest   = (float*)(w + (1u << 20) + 8192 + 2 * 262144);   // 256 KB
    float* xnorm   = (float*)(w + (1u << 20) + 8192 + 3 * 262144);   // 256 KB

    k_prep<<<NB_CODE, 128, 0, stream>>>(cb, cbh, cnorm, hist);
    k_argmin<<<M_ROWS / 128, 256, 0, stream>>>(x, cbh, cnorm, cand, sbest, xnorm);
    k_rescore<<<1024, 256, 0, stream>>>(x, cb, cnorm, cand, idx_final, sbest);
    k_scatter<<<1024, 256, 0, stream>>>(cb, idx_final, dout, hist);
    k_finalize<<<1, 1024, 0, stream>>>(hist, xnorm, sbest, dout);
}

// Round 11
// 202.825 us; speedup vs baseline: 1.1430x; 1.1430x over previous
//
#include <hip/hip_runtime.h>
#include <cstddef>
#include <cstdint>

#define N_BATCH 32
#define WIDTH   512
#define T_DIM   2048
#define NB_CODE 1024
#define M_ROWS  65536
#define OUT_ELEMS 33554432
#define IDX_OFF  OUT_ELEMS
#define LOSS_OFF (OUT_ELEMS + M_ROWS)
#define PERP_OFF (LOSS_OFF + 1)
#define MARGIN   0.75f

typedef __attribute__((ext_vector_type(8))) short vshort8;
typedef __attribute__((ext_vector_type(4))) float vfloat4;
typedef __attribute__((ext_vector_type(16))) float vfloat16;

typedef __attribute__((address_space(1))) const uint32_t gu32_t;
typedef __attribute__((address_space(3))) uint32_t lu32_t;
static __device__ __forceinline__ void gload16(const void* g, void* l) {
    __builtin_amdgcn_global_load_lds((gu32_t*)g, (lu32_t*)l, 16, 0, 0);
}

static __device__ __forceinline__ unsigned short f2bf(float f) {
    uint32_t u = __float_as_uint(f);
    uint32_t r = (u + 0x7FFFu + ((u >> 16) & 1u)) >> 16;  // RNE
    return (unsigned short)r;
}
static __device__ __forceinline__ float bf2f(unsigned short s) {
    return __uint_as_float(((uint32_t)s) << 16);
}

// ---------------- workspace layout (bytes) ----------------
// cbh 1MB | cnorm 4K | hist 4K | cand 256K | idx 256K | sbest 256K | xnorm 256K

// bf16 codebook + per-code norms + hist zeroing.
__global__ __launch_bounds__(128) void k_prep(const float* __restrict__ cb,
                                              unsigned short* __restrict__ cbh,
                                              float* __restrict__ cnorm,
                                              int* __restrict__ hist) {
    const int c = blockIdx.x, tid = threadIdx.x;
    float4 v = ((const float4*)(cb + (size_t)c * WIDTH))[tid];
    ushort4 h;
    h.x = f2bf(v.x); h.y = f2bf(v.y); h.z = f2bf(v.z); h.w = f2bf(v.w);
    ((ushort4*)(cbh + (size_t)c * WIDTH))[tid] = h;
    float s = v.x * v.x + v.y * v.y + v.z * v.z + v.w * v.w;
#pragma unroll
    for (int off = 32; off >= 1; off >>= 1) s += __shfl_xor(s, off, 64);
    __shared__ float sw[2];
    if ((tid & 63) == 0) sw[tid >> 6] = s;
    __syncthreads();
    if (tid == 0) { cnorm[c] = sw[0] + sw[1]; hist[c] = 0; }
}

// hh-screen argmin, 32x32x16 MFMA, fused x load/convert.
// 256 blocks x 512 thr (8 waves), 256 rows/block, 32 rows/wave.
// Codebook streamed as 32 chunks of 64 codes x 256 k (32KB) through a
// 4-buffer LDS ring -> DEPTH-2 prefetch with counted vmcnt(8) waits
// (no full drain until the last phase). LDS 4x32KB + cns = 132KB.
__global__ __launch_bounds__(512, 2) void k_argmin(
    const float* __restrict__ x, const unsigned short* __restrict__ cbh,
    const float* __restrict__ cnorm, uint32_t* __restrict__ cand,
    float* __restrict__ sbest, float* __restrict__ xnorm) {
    __shared__ __align__(16) short lds[4][16384];   // 4 x 32KB ring
    __shared__ __align__(16) float cns[NB_CODE];

    const int tid = threadIdx.x;
    const int wv = tid >> 6, l = tid & 63;
    const int l31 = l & 31, hi = l >> 5;

    // staging source offsets (inverse swizzle). Tile = 64 codes x 256 k:
    // LDS byte = kq*16384 + code*256 + (slot^(code&15))*16, kq=k/128, slot=(k%128)/8
    int srcoff[4];
#pragma unroll
    for (int j = 0; j < 4; ++j) {
        const int q = j * 512 + tid;                 // 16B slot index 0..2047
        const int kq = q >> 10, code = (q >> 4) & 63, sx = q & 15;
        const int slot = sx ^ (code & 15);
        srcoff[j] = code * 1024 + kq * 256 + slot * 16;
    }

#define STAGE(SP, B) do {                                                     \
    const char* cbbase_ = ((const char*)cbh) + ((SP) >> 1) * 65536 + ((SP) & 1) * 512; \
    short* lb_ = &lds[B][0];                                                  \
    _Pragma("unroll")                                                         \
    for (int j = 0; j < 4; ++j)                                               \
        gload16(cbbase_ + srcoff[j], lb_ + (j * 512 + tid) * 8);              \
} while (0)

    STAGE(0, 0);
    STAGE(1, 1);

    { ((float2*)cns)[tid] = ((const float2*)cnorm)[tid]; }

    // ---- fused x load: 32 rows/wave, coalesced f32 (lane=t), cvt_pk to bf16.
    const int m0w = blockIdx.x * 256 + wv * 32;
    const int n = m0w >> 11;
    const int tcol = (m0w & 2047) + l31;
    vshort8 xh[32];
    float xn = 0.f;
    {
        const float* xb = x + (size_t)n * WIDTH * T_DIM + (size_t)hi * 8 * T_DIM + tcol;
        union U8 { uint32_t u[4]; vshort8 v; };
#pragma unroll
        for (int ks = 0; ks < 32; ++ks) {
            U8 u;
#pragma unroll
            for (int j = 0; j < 4; ++j) {
                const float f0 = xb[(size_t)(ks * 16 + 2 * j) * T_DIM];
                const float f1 = xb[(size_t)(ks * 16 + 2 * j + 1) * T_DIM];
                xn = fmaf(f0, f0, fmaf(f1, f1, xn));
                asm("v_cvt_pk_bf16_f32 %0, %1, %2" : "=v"(u.u[j]) : "v"(f0), "v"(f1));
            }
            xh[ks] = u.v;
        }
    }
    xn += __shfl_xor(xn, 32, 64);
    if (l < 32) xnorm[m0w + l] = xn;   // exact fp32 row norm

    const int sxl = l31 & 15;          // read-swizzle XOR source

    float b1 = 3.4e38f, b2 = 3.4e38f, b3 = 3.4e38f;
    int i1 = 0, i2 = 0, i3 = 0;

#define INS3(S, C) do {                                                       \
        const bool lt1 = (S) < b1, lt2 = (S) < b2, lt3 = (S) < b3;            \
        b3 = lt3 ? (lt2 ? b2 : (S)) : b3;  i3 = lt3 ? (lt2 ? i2 : (C)) : i3; \
        b2 = lt2 ? (lt1 ? b1 : (S)) : b2;  i2 = lt2 ? (lt1 ? i1 : (C)) : i2; \
        b1 = lt1 ? (S) : b1;               i1 = lt1 ? (C) : i1;              \
    } while (0)

    __syncthreads();   // startup drain: chunks 0,1 + cns + x loads complete

    for (int cc = 0; cc < 16; ++cc) {
        vfloat16 acc0 = {}, acc1 = {};
#pragma unroll
        for (int kh = 0; kh < 2; ++kh) {
            const int sp = cc * 2 + kh;
            if (sp) {
                // tile sp retired; tile sp+1 (8 loads) may still fly
                if (sp < 31) asm volatile("s_waitcnt vmcnt(8)" ::: "memory");
                else         asm volatile("s_waitcnt vmcnt(0)" ::: "memory");
                __builtin_amdgcn_s_barrier();
            }
            if (sp < 30) {
                STAGE(sp + 2, (sp + 2) & 3);   // depth-2 prefetch into freed buffer
            }
            const short* buf = lds[sp & 3];
            __builtin_amdgcn_s_setprio(1);
#pragma unroll
            for (int ks = 0; ks < 16; ++ks) {
                // k_local = ks*16 + hi*8; kq=ks>>3, slot=((ks&7)<<1)|hi
                const int addr0 = (ks >> 3) * 8192 + l31 * 128 +
                                  (((((ks & 7) << 1) | hi) ^ sxl) << 3);
                vshort8 a0 = *(const vshort8*)&buf[addr0];
                acc0 = __builtin_amdgcn_mfma_f32_32x32x16_bf16(a0, xh[kh * 16 + ks], acc0, 0, 0, 0);
                vshort8 a1 = *(const vshort8*)&buf[addr0 + 4096];
                acc1 = __builtin_amdgcn_mfma_f32_32x32x16_bf16(a1, xh[kh * 16 + ks], acc1, 0, 0, 0);
            }
            __builtin_amdgcn_s_setprio(0);
        }
        // score 64 codes: D[code][row], col=lane&31=row, code=(r&3)+8*(r>>2)+4*hi
        const int cb0 = cc * 64;
#pragma unroll
        for (int tl = 0; tl < 2; ++tl) {
#pragma unroll
            for (int g = 0; g < 4; ++g) {
                const int cbase = cb0 + tl * 32 + g * 8 + 4 * hi;
                vfloat4 cn = *(const vfloat4*)&cns[cbase];
#pragma unroll
                for (int j = 0; j < 4; ++j) {
                    const float a = tl ? acc1[g * 4 + j] : acc0[g * 4 + j];
                    const float s = fmaf(-2.f, a, cn[j]);
                    INS3(s, cbase + j);
                }
            }
        }
    }

    // merge top-3 across the hi halves (disjoint code sets)
    {
        const float ob1 = __shfl_xor(b1, 32, 64), ob2 = __shfl_xor(b2, 32, 64), ob3 = __shfl_xor(b3, 32, 64);
        const int oi1 = __shfl_xor(i1, 32, 64), oi2 = __shfl_xor(i2, 32, 64), oi3 = __shfl_xor(i3, 32, 64);
        INS3(ob1, oi1); INS3(ob2, oi2); INS3(ob3, oi3);
    }
    if (l < 32) {
        const uint32_t f2 = (b2 - b1 < MARGIN) ? 1u : 0u;
        const uint32_t f3 = (b3 - b1 < MARGIN) ? 1u : 0u;
        cand[m0w + l] = (uint32_t)i1 | ((uint32_t)i2 << 10) | ((uint32_t)i3 << 20) | (f2 << 30) | (f3 << 31);
        sbest[m0w + l] = b1;   // screen-score of winner (overwritten if rescored)
    }
}

// EXACT fp32 rescore of flagged rows (original x + fp32 cb), one wave/row.
// Writes final idx + exact winning score.
__global__ __launch_bounds__(256) void k_rescore(
    const float* __restrict__ x, const float* __restrict__ cb,
    const float* __restrict__ cnorm, const uint32_t* __restrict__ cand,
    int* __restrict__ idx_final, float* __restrict__ sbest) {
    __shared__ int list[64];
    __shared__ int cnt;
    const int tid = threadIdx.x;
    const int m0 = blockIdx.x * 64;
    if (tid == 0) cnt = 0;
    __syncthreads();
    if (tid < 64) {
        const uint32_t wv = cand[m0 + tid];
        if (wv >> 30) { const int p = atomicAdd(&cnt, 1); list[p] = tid; }
        else idx_final[m0 + tid] = (int)(wv & 1023u);
    }
    __syncthreads();
    const int nf = cnt;
    const int w = tid >> 6, lid = tid & 63;
    for (int it = w; it < nf; it += 4) {
        const int row = m0 + list[it];
        const uint32_t wv = cand[row];
        const int j1 = (int)(wv & 1023u), j2 = (int)((wv >> 10) & 1023u), j3 = (int)((wv >> 20) & 1023u);
        const bool nd3 = (wv >> 31) & 1u;
        const int n = row >> 11, t = row & 2047;
        const float* xc = x + (size_t)n * WIDTH * T_DIM + t;
        float xv[8];
#pragma unroll
        for (int e = 0; e < 8; ++e)
            xv[e] = xc[(size_t)(lid * 8 + e) * T_DIM];
        float d1 = 0.f, d2 = 0.f, d3 = 0.f;
        {
            const float* c1 = cb + (size_t)j1 * WIDTH + lid * 8;
            const float* c2 = cb + (size_t)j2 * WIDTH + lid * 8;
            const float* c3 = cb + (size_t)j3 * WIDTH + lid * 8;
            float4 a0 = *(const float4*)c1, a1 = *(const float4*)(c1 + 4);
            d1 = fmaf(xv[0], a0.x, fmaf(xv[1], a0.y, fmaf(xv[2], a0.z, fmaf(xv[3], a0.w,
                 fmaf(xv[4], a1.x, fmaf(xv[5], a1.y, fmaf(xv[6], a1.z, xv[7] * a1.w)))))));
            float4 b0 = *(const float4*)c2, b1v = *(const float4*)(c2 + 4);
            d2 = fmaf(xv[0], b0.x, fmaf(xv[1], b0.y, fmaf(xv[2], b0.z, fmaf(xv[3], b0.w,
                 fmaf(xv[4], b1v.x, fmaf(xv[5], b1v.y, fmaf(xv[6], b1v.z, xv[7] * b1v.w)))))));
            if (nd3) {
                float4 g0 = *(const float4*)c3, g1 = *(const float4*)(c3 + 4);
                d3 = fmaf(xv[0], g0.x, fmaf(xv[1], g0.y, fmaf(xv[2], g0.z, fmaf(xv[3], g0.w,
                     fmaf(xv[4], g1.x, fmaf(xv[5], g1.y, fmaf(xv[6], g1.z, xv[7] * g1.w)))))));
            }
        }
#pragma unroll
        for (int off = 32; off >= 1; off >>= 1) {
            d1 += __shfl_xor(d1, off, 64);
            d2 += __shfl_xor(d2, off, 64);
            d3 += __shfl_xor(d3, off, 64);
        }
        if (lid == 0) {
            int win = j1;
            float qw = fmaf(-2.f, d1, cnorm[j1]);
            const float q2 = fmaf(-2.f, d2, cnorm[j2]);
            if (q2 < qw || (q2 == qw && j2 < win)) { win = j2; qw = q2; }
            if (nd3) {
                const float q3 = fmaf(-2.f, d3, cnorm[j3]);
                if (q3 < qw || (q3 == qw && j3 < win)) { win = j3; qw = q3; }
            }
            idx_final[row] = win;
            sbest[row] = qw;
        }
    }
}

// Gather codebook[idx] -> out [N][W][T] via LDS transpose staging,
// idx as float, histogram. (No x reads -- loss comes from the dist identity.)
__global__ __launch_bounds__(256) void k_scatter(
    const float* __restrict__ cb, const int* __restrict__ idx,
    float* __restrict__ dout, int* __restrict__ hist) {
    __shared__ int sidx[64];
    __shared__ float tile[64][130];
    const int tid = threadIdx.x;
    const int b = blockIdx.x;
    const int n = b >> 5;
    const int t0 = (b & 31) * 64;
    if (tid < 64) {
        const int m2 = n * T_DIM + t0 + tid;
        const int ii = idx[m2];
        sidx[tid] = ii;
        dout[IDX_OFF + m2] = (float)ii;
        atomicAdd(&hist[ii], 1);
    }
    __syncthreads();
    const int w = tid >> 6, l = tid & 63;
    for (int wc = 0; wc < 4; ++wc) {
#pragma unroll
        for (int rr = 0; rr < 16; ++rr) {
            const int row = w * 16 + rr;
            const float2 v = *(const float2*)(cb + (size_t)sidx[row] * WIDTH + wc * 128 + l * 2);
            *(float2*)&tile[row][l * 2] = v;
        }
        __syncthreads();
#pragma unroll 8
        for (int wwi = 0; wwi < 32; ++wwi) {
            const int ww = wc * 128 + w * 32 + wwi;
            dout[((size_t)n * WIDTH + ww) * T_DIM + t0 + l] = tile[l][w * 32 + wwi];
        }
        __syncthreads();
    }
}

// perplexity from hist + commit loss = sum(xnorm + s_win) / OUT_ELEMS
__global__ __launch_bounds__(1024) void k_finalize(
    const int* __restrict__ hist, const float* __restrict__ xnorm,
    const float* __restrict__ sbest, float* __restrict__ dout) {
    const int tid = threadIdx.x;
    float e;
    {
        const float p = (float)hist[tid] * (1.0f / (float)M_ROWS);
        e = p * logf(p + 1e-7f);
    }
    float ls = 0.f;
    for (int i = tid; i < M_ROWS; i += 1024) ls += xnorm[i] + sbest[i];
#pragma unroll
    for (int off = 32; off >= 1; off >>= 1) {
        e += __shfl_xor(e, off, 64);
        ls += __shfl_xor(ls, off, 64);
    }
    __shared__ float se[16], sl[16];
    if ((tid & 63) == 0) { se[tid >> 6] = e; sl[tid >> 6] = ls; }
    __syncthreads();
    if (tid == 0) {
        float E = 0.f, L = 0.f;
#pragma unroll
        for (int i = 0; i < 16; ++i) { E += se[i]; L += sl[i]; }
        dout[LOSS_OFF] = L / (float)OUT_ELEMS;
        dout[PERP_OFF] = expf(-E);
    }
}

extern "C" void kernel_launch(void* const* d_in, const int* in_sizes, int n_in,
                              void* d_out, int out_size, void* d_ws, size_t ws_size,
                              hipStream_t stream) {
    const float* x = (const float*)d_in[0];
    const float* cb = (const float*)d_in[1];
    float* dout = (float*)d_out;
    uint8_t* w = (uint8_t*)d_ws;

    unsigned short* cbh = (unsigned short*)w;                        // 1 MB
    float* cnorm   = (float*)(w + (1u << 20));                       // 4 KB
    int*   hist    = (int*)(w + (1u << 20) + 4096);                  // 4 KB
    uint32_t* cand = (uint32_t*)(w + (1u << 20) + 8192);             // 256 KB
    int* idx_final = (int*)(w + (1u << 20) + 8192 + 262144);         // 256 KB
    float* sbest   = (float*)(w + (1u << 20) + 8192 + 2 * 262144);   // 256 KB
    float* xnorm   = (float*)(w + (1u << 20) + 8192 + 3 * 262144);   // 256 KB

    k_prep<<<NB_CODE, 128, 0, stream>>>(cb, cbh, cnorm, hist);
    k_argmin<<<M_ROWS / 256, 512, 0, stream>>>(x, cbh, cnorm, cand, sbest, xnorm);
    k_rescore<<<1024, 256, 0, stream>>>(x, cb, cnorm, cand, idx_final, sbest);
    k_scatter<<<1024, 256, 0, stream>>>(cb, idx_final, dout, hist);
    k_finalize<<<1, 1024, 0, stream>>>(hist, xnorm, sbest, dout);
}

// Round 12
// 170.994 us; speedup vs baseline: 1.3558x; 1.1862x over previous
//
#include <hip/hip_runtime.h>
#include <cstddef>
#include <cstdint>

#define N_BATCH 32
#define WIDTH   512
#define T_DIM   2048
#define NB_CODE 1024
#define M_ROWS  65536
#define OUT_ELEMS 33554432
#define IDX_OFF  OUT_ELEMS
#define LOSS_OFF (OUT_ELEMS + M_ROWS)
#define PERP_OFF (LOSS_OFF + 1)
#define MARGIN   0.75f

typedef __attribute__((ext_vector_type(8))) short vshort8;
typedef __attribute__((ext_vector_type(4))) float vfloat4;
typedef __attribute__((ext_vector_type(16))) float vfloat16;

typedef __attribute__((address_space(1))) const uint32_t gu32_t;
typedef __attribute__((address_space(3))) uint32_t lu32_t;
static __device__ __forceinline__ void gload16(const void* g, void* l) {
    __builtin_amdgcn_global_load_lds((gu32_t*)g, (lu32_t*)l, 16, 0, 0);
}

static __device__ __forceinline__ unsigned short f2bf(float f) {
    uint32_t u = __float_as_uint(f);
    uint32_t r = (u + 0x7FFFu + ((u >> 16) & 1u)) >> 16;  // RNE
    return (unsigned short)r;
}
static __device__ __forceinline__ float bf2f(unsigned short s) {
    return __uint_as_float(((uint32_t)s) << 16);
}

// ---------------- workspace layout (bytes) ----------------
// cbh 1MB | cnorm 4K | hist 4K | cand 256K | sbest 256K | xnorm 256K | lossPart 4K

// bf16 codebook + per-code norms + hist zeroing.
__global__ __launch_bounds__(128) void k_prep(const float* __restrict__ cb,
                                              unsigned short* __restrict__ cbh,
                                              float* __restrict__ cnorm,
                                              int* __restrict__ hist) {
    const int c = blockIdx.x, tid = threadIdx.x;
    float4 v = ((const float4*)(cb + (size_t)c * WIDTH))[tid];
    ushort4 h;
    h.x = f2bf(v.x); h.y = f2bf(v.y); h.z = f2bf(v.z); h.w = f2bf(v.w);
    ((ushort4*)(cbh + (size_t)c * WIDTH))[tid] = h;
    float s = v.x * v.x + v.y * v.y + v.z * v.z + v.w * v.w;
#pragma unroll
    for (int off = 32; off >= 1; off >>= 1) s += __shfl_xor(s, off, 64);
    __shared__ float sw[2];
    if ((tid & 63) == 0) sw[tid >> 6] = s;
    __syncthreads();
    if (tid == 0) { cnorm[c] = sw[0] + sw[1]; hist[c] = 0; }
}

// hh-screen argmin, 32x32x16 MFMA, fused x load/convert (r9-proven shape).
// 256 blocks x 512 thr (8 waves), 256 rows/block, 32 rows/wave.
// Codebook streamed in 16 chunks of 64 codes x 512 k (64KB), double-buffered;
// ONE barrier + ONE vmcnt(0) per chunk. LDS [kb][code][128 bf16] with
// ^((code&15)<<4) swizzle -> 2-way (free).
__global__ __launch_bounds__(512, 2) void k_argmin(
    const float* __restrict__ x, const unsigned short* __restrict__ cbh,
    const float* __restrict__ cnorm, uint32_t* __restrict__ cand,
    float* __restrict__ sbest, float* __restrict__ xnorm) {
    __shared__ __align__(16) short lds[2][32768];   // 2 x 64KB
    __shared__ __align__(16) float cns[NB_CODE];

    const int tid = threadIdx.x;
    const int wv = tid >> 6, l = tid & 63;
    const int l31 = l & 31, hi = l >> 5;
    const int m = l31 & 15;

    // staging source offsets (inverse swizzle), lds linear slot q = wv*512+j*64+l
    int srcoff[8];
#pragma unroll
    for (int j = 0; j < 8; ++j) {
        const int q = wv * 512 + j * 64 + l;
        const int kb = q >> 10, code = (q >> 4) & 63, s = q & 15;
        srcoff[j] = code * 1024 + kb * 256 + ((s ^ (code & 15)) << 4);
    }

#define STAGE(SP, B) do {                                                     \
    const char* cbbase_ = ((const char*)cbh) + (SP) * 65536;                  \
    short* lb_ = &lds[B][0];                                                  \
    _Pragma("unroll")                                                         \
    for (int j = 0; j < 8; ++j)                                               \
        gload16(cbbase_ + srcoff[j], lb_ + (wv * 512 + j * 64) * 8);          \
} while (0)

    STAGE(0, 0);

    { ((float2*)cns)[tid] = ((const float2*)cnorm)[tid]; }

    // ---- fused x load: 32 rows/wave, coalesced f32 (lane=t), cvt_pk to bf16.
    const int m0w = blockIdx.x * 256 + wv * 32;
    const int n = m0w >> 11;
    const int tcol = (m0w & 2047) + l31;
    vshort8 xh[32];
    float xn = 0.f;
    {
        const float* xb = x + (size_t)n * WIDTH * T_DIM + (size_t)hi * 8 * T_DIM + tcol;
        union U8 { uint32_t u[4]; vshort8 v; };
#pragma unroll
        for (int ks = 0; ks < 32; ++ks) {
            U8 u;
#pragma unroll
            for (int j = 0; j < 4; ++j) {
                const float f0 = xb[(size_t)(ks * 16 + 2 * j) * T_DIM];
                const float f1 = xb[(size_t)(ks * 16 + 2 * j + 1) * T_DIM];
                xn = fmaf(f0, f0, fmaf(f1, f1, xn));
                asm("v_cvt_pk_bf16_f32 %0, %1, %2" : "=v"(u.u[j]) : "v"(f0), "v"(f1));
            }
            xh[ks] = u.v;
        }
    }
    xn += __shfl_xor(xn, 32, 64);
    if (l < 32) xnorm[m0w + l] = xn;   // exact fp32 row norm

    // swizzled ds_read base (shorts): row=tl*32+l31 (256B rows), slot XOR
    const int B34 = (m >> 1) << 4;
    const int base_s = l31 * 128 + ((hi ^ (m & 1)) << 3);

    float b1 = 3.4e38f, b2 = 3.4e38f, b3 = 3.4e38f;
    int i1 = 0, i2 = 0, i3 = 0;

#define INS3(S, C) do {                                                       \
        const bool lt1 = (S) < b1, lt2 = (S) < b2, lt3 = (S) < b3;            \
        b3 = lt3 ? (lt2 ? b2 : (S)) : b3;  i3 = lt3 ? (lt2 ? i2 : (C)) : i3; \
        b2 = lt2 ? (lt1 ? b1 : (S)) : b2;  i2 = lt2 ? (lt1 ? i1 : (C)) : i2; \
        b1 = lt1 ? (S) : b1;               i1 = lt1 ? (C) : i1;              \
    } while (0)

    __syncthreads();   // full drain: chunk0, cns, x loads

    for (int sp = 0; sp < 16; ++sp) {
        if (sp) {
            asm volatile("s_waitcnt vmcnt(0)" ::: "memory");  // own STAGE(sp) done
            __builtin_amdgcn_s_barrier();                     // everyone's done
        }
        if (sp < 15) {
            if (sp & 1) STAGE(sp + 1, 0); else STAGE(sp + 1, 1);
        }
        const short* buf = lds[sp & 1];
        vfloat16 acc0 = {}, acc1 = {};
        __builtin_amdgcn_s_setprio(1);
#pragma unroll
        for (int ks = 0; ks < 32; ++ks) {
            const int koff = ((ks >> 3) << 13) + (((ks & 7) << 4) ^ B34);
            vshort8 a0 = *(const vshort8*)&buf[base_s + koff];
            acc0 = __builtin_amdgcn_mfma_f32_32x32x16_bf16(a0, xh[ks], acc0, 0, 0, 0);
            vshort8 a1 = *(const vshort8*)&buf[base_s + koff + 4096];
            acc1 = __builtin_amdgcn_mfma_f32_32x32x16_bf16(a1, xh[ks], acc1, 0, 0, 0);
        }
        __builtin_amdgcn_s_setprio(0);
        // score 64 codes: D[code][xrow], col=lane&31=row, code=(r&3)+8*(r>>2)+4*hi
        const int cb0 = sp * 64;
#pragma unroll
        for (int tl = 0; tl < 2; ++tl) {
#pragma unroll
            for (int g = 0; g < 4; ++g) {
                const int cbase = cb0 + tl * 32 + g * 8 + 4 * hi;
                vfloat4 cn = *(const vfloat4*)&cns[cbase];
#pragma unroll
                for (int j = 0; j < 4; ++j) {
                    const float a = tl ? acc1[g * 4 + j] : acc0[g * 4 + j];
                    const float s = fmaf(-2.f, a, cn[j]);
                    INS3(s, cbase + j);
                }
            }
        }
    }

    // merge top-3 across the hi halves (disjoint code sets)
    {
        const float ob1 = __shfl_xor(b1, 32, 64), ob2 = __shfl_xor(b2, 32, 64), ob3 = __shfl_xor(b3, 32, 64);
        const int oi1 = __shfl_xor(i1, 32, 64), oi2 = __shfl_xor(i2, 32, 64), oi3 = __shfl_xor(i3, 32, 64);
        INS3(ob1, oi1); INS3(ob2, oi2); INS3(ob3, oi3);
    }
    if (l < 32) {
        const uint32_t f2 = (b2 - b1 < MARGIN) ? 1u : 0u;
        const uint32_t f3 = (b3 - b1 < MARGIN) ? 1u : 0u;
        cand[m0w + l] = (uint32_t)i1 | ((uint32_t)i2 << 10) | ((uint32_t)i3 << 20) | (f2 << 30) | (f3 << 31);
        sbest[m0w + l] = b1;   // screen-score of winner
    }
}

// Fused tail: exact fp32 rescore of flagged rows (into LDS) + gather/scatter
// out + idx write + histogram + per-block commit-loss partial.
__global__ __launch_bounds__(256) void k_tail(
    const float* __restrict__ x, const float* __restrict__ cb,
    const float* __restrict__ cnorm, const uint32_t* __restrict__ cand,
    const float* __restrict__ sbest, const float* __restrict__ xnorm,
    float* __restrict__ dout, int* __restrict__ hist,
    float* __restrict__ lossPart) {
    __shared__ int sidx[64];
    __shared__ float sls[64];
    __shared__ int list[64];
    __shared__ int cnt;
    __shared__ float tile[64][130];
    const int tid = threadIdx.x;
    const int b = blockIdx.x;
    const int m0 = b * 64;
    if (tid == 0) cnt = 0;
    __syncthreads();
    if (tid < 64) {
        const uint32_t wv = cand[m0 + tid];
        sidx[tid] = (int)(wv & 1023u);
        sls[tid] = xnorm[m0 + tid] + sbest[m0 + tid];
        if (wv >> 30) { const int p = atomicAdd(&cnt, 1); list[p] = tid; }
    }
    __syncthreads();
    const int nf = cnt;
    const int w = tid >> 6, lid = tid & 63;
    for (int it = w; it < nf; it += 4) {
        const int row = m0 + list[it];
        const uint32_t wv = cand[row];
        const int j1 = (int)(wv & 1023u), j2 = (int)((wv >> 10) & 1023u), j3 = (int)((wv >> 20) & 1023u);
        const bool nd3 = (wv >> 31) & 1u;
        const int n = row >> 11, t = row & 2047;
        const float* xc = x + (size_t)n * WIDTH * T_DIM + t;
        float xv[8];
#pragma unroll
        for (int e = 0; e < 8; ++e)
            xv[e] = xc[(size_t)(lid * 8 + e) * T_DIM];
        float d1 = 0.f, d2 = 0.f, d3 = 0.f;
        {
            const float* c1 = cb + (size_t)j1 * WIDTH + lid * 8;
            const float* c2 = cb + (size_t)j2 * WIDTH + lid * 8;
            const float* c3 = cb + (size_t)j3 * WIDTH + lid * 8;
            float4 a0 = *(const float4*)c1, a1 = *(const float4*)(c1 + 4);
            d1 = fmaf(xv[0], a0.x, fmaf(xv[1], a0.y, fmaf(xv[2], a0.z, fmaf(xv[3], a0.w,
                 fmaf(xv[4], a1.x, fmaf(xv[5], a1.y, fmaf(xv[6], a1.z, xv[7] * a1.w)))))));
            float4 b0 = *(const float4*)c2, b1v = *(const float4*)(c2 + 4);
            d2 = fmaf(xv[0], b0.x, fmaf(xv[1], b0.y, fmaf(xv[2], b0.z, fmaf(xv[3], b0.w,
                 fmaf(xv[4], b1v.x, fmaf(xv[5], b1v.y, fmaf(xv[6], b1v.z, xv[7] * b1v.w)))))));
            if (nd3) {
                float4 g0 = *(const float4*)c3, g1 = *(const float4*)(c3 + 4);
                d3 = fmaf(xv[0], g0.x, fmaf(xv[1], g0.y, fmaf(xv[2], g0.z, fmaf(xv[3], g0.w,
                     fmaf(xv[4], g1.x, fmaf(xv[5], g1.y, fmaf(xv[6], g1.z, xv[7] * g1.w)))))));
            }
        }
#pragma unroll
        for (int off = 32; off >= 1; off >>= 1) {
            d1 += __shfl_xor(d1, off, 64);
            d2 += __shfl_xor(d2, off, 64);
            d3 += __shfl_xor(d3, off, 64);
        }
        if (lid == 0) {
            int win = j1;
            float qw = fmaf(-2.f, d1, cnorm[j1]);
            const float q2 = fmaf(-2.f, d2, cnorm[j2]);
            if (q2 < qw || (q2 == qw && j2 < win)) { win = j2; qw = q2; }
            if (nd3) {
                const float q3 = fmaf(-2.f, d3, cnorm[j3]);
                if (q3 < qw || (q3 == qw && j3 < win)) { win = j3; qw = q3; }
            }
            sidx[list[it]] = win;
            sls[list[it]] = xnorm[row] + qw;
        }
    }
    __syncthreads();
    if (tid < 64) {
        dout[IDX_OFF + m0 + tid] = (float)sidx[tid];
        atomicAdd(&hist[sidx[tid]], 1);
        float ls = sls[tid];
#pragma unroll
        for (int off = 32; off >= 1; off >>= 1) ls += __shfl_xor(ls, off, 64);
        if (tid == 0) lossPart[b] = ls;
    }
    // scatter: codebook[sidx] -> out [N][W][T] via LDS transpose staging
    const int n = b >> 5;
    const int t0 = (b & 31) * 64;
    const int l = tid & 63;
    for (int wc = 0; wc < 4; ++wc) {
#pragma unroll
        for (int rr = 0; rr < 16; ++rr) {
            const int row = w * 16 + rr;
            const float2 v = *(const float2*)(cb + (size_t)sidx[row] * WIDTH + wc * 128 + l * 2);
            *(float2*)&tile[row][l * 2] = v;
        }
        __syncthreads();
#pragma unroll 8
        for (int wwi = 0; wwi < 32; ++wwi) {
            const int ww = wc * 128 + w * 32 + wwi;
            dout[((size_t)n * WIDTH + ww) * T_DIM + t0 + l] = tile[l][w * 32 + wwi];
        }
        __syncthreads();
    }
}

// perplexity from hist + commit loss from 1024 block partials
__global__ __launch_bounds__(1024) void k_fin(
    const int* __restrict__ hist, const float* __restrict__ lossPart,
    float* __restrict__ dout) {
    const int tid = threadIdx.x;
    const float p = (float)hist[tid] * (1.0f / (float)M_ROWS);
    float e = p * logf(p + 1e-7f);
    float ls = lossPart[tid];
#pragma unroll
    for (int off = 32; off >= 1; off >>= 1) {
        e += __shfl_xor(e, off, 64);
        ls += __shfl_xor(ls, off, 64);
    }
    __shared__ float se[16], sl[16];
    if ((tid & 63) == 0) { se[tid >> 6] = e; sl[tid >> 6] = ls; }
    __syncthreads();
    if (tid == 0) {
        float E = 0.f, L = 0.f;
#pragma unroll
        for (int i = 0; i < 16; ++i) { E += se[i]; L += sl[i]; }
        dout[LOSS_OFF] = L / (float)OUT_ELEMS;
        dout[PERP_OFF] = expf(-E);
    }
}

extern "C" void kernel_launch(void* const* d_in, const int* in_sizes, int n_in,
                              void* d_out, int out_size, void* d_ws, size_t ws_size,
                              hipStream_t stream) {
    const float* x = (const float*)d_in[0];
    const float* cb = (const float*)d_in[1];
    float* dout = (float*)d_out;
    uint8_t* w = (uint8_t*)d_ws;

    unsigned short* cbh = (unsigned short*)w;                        // 1 MB
    float* cnorm   = (float*)(w + (1u << 20));                       // 4 KB
    int*   hist    = (int*)(w + (1u << 20) + 4096);                  // 4 KB
    uint32_t* cand = (uint32_t*)(w + (1u << 20) + 8192);             // 256 KB
    float* sbest   = (float*)(w + (1u << 20) + 8192 + 262144);       // 256 KB
    float* xnorm   = (float*)(w + (1u << 20) + 8192 + 2 * 262144);   // 256 KB
    float* lossPart= (float*)(w + (1u << 20) + 8192 + 3 * 262144);   // 4 KB

    k_prep<<<NB_CODE, 128, 0, stream>>>(cb, cbh, cnorm, hist);
    k_argmin<<<M_ROWS / 256, 512, 0, stream>>>(x, cbh, cnorm, cand, sbest, xnorm);
    k_tail<<<1024, 256, 0, stream>>>(x, cb, cnorm, cand, sbest, xnorm, dout, hist, lossPart);
    k_fin<<<1, 1024, 0, stream>>>(hist, lossPart, dout);
}

// Round 13
// 162.521 us; speedup vs baseline: 1.4264x; 1.0521x over previous
//
#include <hip/hip_runtime.h>
#include <cstddef>
#include <cstdint>

#define N_BATCH 32
#define WIDTH   512
#define T_DIM   2048
#define NB_CODE 1024
#define M_ROWS  65536
#define OUT_ELEMS 33554432
#define IDX_OFF  OUT_ELEMS
#define LOSS_OFF (OUT_ELEMS + M_ROWS)
#define PERP_OFF (LOSS_OFF + 1)
#define MARGIN   0.75f

typedef __attribute__((ext_vector_type(8))) short vshort8;
typedef __attribute__((ext_vector_type(4))) float vfloat4;
typedef __attribute__((ext_vector_type(16))) float vfloat16;

typedef __attribute__((address_space(1))) const uint32_t gu32_t;
typedef __attribute__((address_space(3))) uint32_t lu32_t;
static __device__ __forceinline__ void gload16(const void* g, void* l) {
    __builtin_amdgcn_global_load_lds((gu32_t*)g, (lu32_t*)l, 16, 0, 0);
}

static __device__ __forceinline__ unsigned short f2bf(float f) {
    uint32_t u = __float_as_uint(f);
    uint32_t r = (u + 0x7FFFu + ((u >> 16) & 1u)) >> 16;  // RNE
    return (unsigned short)r;
}

// ---------------- workspace layout (bytes) ----------------
// cbh 1MB | cnorm 4K | hist 4K | cand 256K | sbest 256K | xnorm 256K | lossPart 4K

// bf16 codebook + per-code norms + hist zeroing.
__global__ __launch_bounds__(128) void k_prep(const float* __restrict__ cb,
                                              unsigned short* __restrict__ cbh,
                                              float* __restrict__ cnorm,
                                              int* __restrict__ hist) {
    const int c = blockIdx.x, tid = threadIdx.x;
    float4 v = ((const float4*)(cb + (size_t)c * WIDTH))[tid];
    ushort4 h;
    h.x = f2bf(v.x); h.y = f2bf(v.y); h.z = f2bf(v.z); h.w = f2bf(v.w);
    ((ushort4*)(cbh + (size_t)c * WIDTH))[tid] = h;
    float s = v.x * v.x + v.y * v.y + v.z * v.z + v.w * v.w;
#pragma unroll
    for (int off = 32; off >= 1; off >>= 1) s += __shfl_xor(s, off, 64);
    __shared__ float sw[2];
    if ((tid & 63) == 0) sw[tid >> 6] = s;
    __syncthreads();
    if (tid == 0) { cnorm[c] = sw[0] + sw[1]; hist[c] = 0; }
}

// hh-screen argmin, 32x32x16 MFMA, fused x load/convert.
// 512 blocks x 256 thr (4 waves), 128 rows/block, 32 rows/wave.
// Codebook chunk = 32 codes x 512 k (32KB), double-buffered = EXACTLY 64KB
// LDS (no cns array; cnorm scored from L1) -> TWO independent 4-wave blocks
// per CU whose barrier stalls interleave. 32 phases, depth-1 prefetch,
// one vmcnt(0)+barrier per phase.
__global__ __launch_bounds__(256, 2) void k_argmin(
    const float* __restrict__ x, const unsigned short* __restrict__ cbh,
    const float* __restrict__ cnorm, uint32_t* __restrict__ cand,
    float* __restrict__ sbest, float* __restrict__ xnorm) {
    __shared__ __align__(16) short lds[2][16384];   // 2 x 32KB = 64KB total

    const int tid = threadIdx.x;
    const int wv = tid >> 6, l = tid & 63;
    const int l31 = l & 31, hi = l >> 5;

    // staging source offsets (inverse swizzle). Chunk = 32 codes x 512 k:
    // LDS 16B-slot q -> code=q>>6? : code = q/64? ... q in 0..2047:
    // code = q >> 6 is wrong; per code 64 slots: code=q>>6 (32 codes x 64 slots).
    // slot-in-code w = q & 63: kb = w >> 4 (4 x 128-k blocks), s = w & 15.
    // global byte = code*1024 + kb*256 + (s ^ (code & 15))*16
    int srcoff[8];
#pragma unroll
    for (int j = 0; j < 8; ++j) {
        const int q = j * 256 + tid;
        const int code = q >> 6, w = q & 63;
        const int kb = w >> 4, s = w & 15;
        srcoff[j] = code * 1024 + kb * 256 + ((s ^ (code & 15)) << 4);
    }

#define STAGE(SP, B) do {                                                     \
    const char* cbbase_ = ((const char*)cbh) + (size_t)(SP) * 32768;          \
    short* lb_ = &lds[B][0];                                                  \
    _Pragma("unroll")                                                         \
    for (int j = 0; j < 8; ++j)                                               \
        gload16(cbbase_ + srcoff[j], lb_ + (j * 256 + tid) * 8);              \
} while (0)

    STAGE(0, 0);

    // ---- fused x load: 32 rows/wave, coalesced f32 (lane=t), cvt_pk to bf16.
    const int m0w = blockIdx.x * 128 + wv * 32;
    const int n = m0w >> 11;
    const int tcol = (m0w & 2047) + l31;
    vshort8 xh[32];
    float xn = 0.f;
    {
        const float* xb = x + (size_t)n * WIDTH * T_DIM + (size_t)hi * 8 * T_DIM + tcol;
        union U8 { uint32_t u[4]; vshort8 v; };
#pragma unroll
        for (int ks = 0; ks < 32; ++ks) {
            U8 u;
#pragma unroll
            for (int j = 0; j < 4; ++j) {
                const float f0 = xb[(size_t)(ks * 16 + 2 * j) * T_DIM];
                const float f1 = xb[(size_t)(ks * 16 + 2 * j + 1) * T_DIM];
                xn = fmaf(f0, f0, fmaf(f1, f1, xn));
                asm("v_cvt_pk_bf16_f32 %0, %1, %2" : "=v"(u.u[j]) : "v"(f0), "v"(f1));
            }
            xh[ks] = u.v;
        }
    }
    xn += __shfl_xor(xn, 32, 64);
    if (l < 32) xnorm[m0w + l] = xn;   // exact fp32 row norm

    const int sxl = l31 & 15;          // read-swizzle XOR source
    const int rbase = l31 * 512;       // code row base (shorts)

    float b1 = 3.4e38f, b2 = 3.4e38f, b3 = 3.4e38f;
    int i1 = 0, i2 = 0, i3 = 0;

#define INS3(S, C) do {                                                       \
        const bool lt1 = (S) < b1, lt2 = (S) < b2, lt3 = (S) < b3;            \
        b3 = lt3 ? (lt2 ? b2 : (S)) : b3;  i3 = lt3 ? (lt2 ? i2 : (C)) : i3; \
        b2 = lt2 ? (lt1 ? b1 : (S)) : b2;  i2 = lt2 ? (lt1 ? i1 : (C)) : i2; \
        b1 = lt1 ? (S) : b1;               i1 = lt1 ? (C) : i1;              \
    } while (0)

    __syncthreads();   // startup drain: chunk0 + x loads complete

    for (int sp = 0; sp < 32; ++sp) {
        if (sp) {
            asm volatile("s_waitcnt vmcnt(0)" ::: "memory");  // own STAGE(sp) done
            __builtin_amdgcn_s_barrier();                     // everyone's done
        }
        if (sp < 31) {
            if (sp & 1) STAGE(sp + 1, 0); else STAGE(sp + 1, 1);
        }
        const short* buf = lds[sp & 1];
        vfloat16 acc = {};
        __builtin_amdgcn_s_setprio(1);
#pragma unroll
        for (int ks = 0; ks < 32; ++ks) {
            // k = ks*16 + hi*8; kb=ks>>3, slot=((ks&7)<<1)|hi, swz ^ sxl
            const int addr = rbase + (ks >> 3) * 128 +
                             (((((ks & 7) << 1) | hi) ^ sxl) << 3);
            vshort8 a = *(const vshort8*)&buf[addr];
            acc = __builtin_amdgcn_mfma_f32_32x32x16_bf16(a, xh[ks], acc, 0, 0, 0);
        }
        __builtin_amdgcn_s_setprio(0);
        // score 32 codes: D[code][row], col=lane&31=row, code=(r&3)+8*(r>>2)+4*hi
        const int cb0 = sp * 32;
#pragma unroll
        for (int g = 0; g < 4; ++g) {
            const int cbase = cb0 + g * 8 + 4 * hi;
            const vfloat4 cn = *(const vfloat4*)&cnorm[cbase];
#pragma unroll
            for (int j = 0; j < 4; ++j) {
                const float s = fmaf(-2.f, acc[g * 4 + j], cn[j]);
                INS3(s, cbase + j);
            }
        }
    }

    // merge top-3 across the hi halves (disjoint code sets)
    {
        const float ob1 = __shfl_xor(b1, 32, 64), ob2 = __shfl_xor(b2, 32, 64), ob3 = __shfl_xor(b3, 32, 64);
        const int oi1 = __shfl_xor(i1, 32, 64), oi2 = __shfl_xor(i2, 32, 64), oi3 = __shfl_xor(i3, 32, 64);
        INS3(ob1, oi1); INS3(ob2, oi2); INS3(ob3, oi3);
    }
    if (l < 32) {
        const uint32_t f2 = (b2 - b1 < MARGIN) ? 1u : 0u;
        const uint32_t f3 = (b3 - b1 < MARGIN) ? 1u : 0u;
        cand[m0w + l] = (uint32_t)i1 | ((uint32_t)i2 << 10) | ((uint32_t)i3 << 20) | (f2 << 30) | (f3 << 31);
        sbest[m0w + l] = b1;   // screen-score of winner
    }
}

// Fused tail: exact fp32 rescore of flagged rows (into LDS) + gather/scatter
// out + idx write + histogram + per-block commit-loss partial.
__global__ __launch_bounds__(256) void k_tail(
    const float* __restrict__ x, const float* __restrict__ cb,
    const float* __restrict__ cnorm, const uint32_t* __restrict__ cand,
    const float* __restrict__ sbest, const float* __restrict__ xnorm,
    float* __restrict__ dout, int* __restrict__ hist,
    float* __restrict__ lossPart) {
    __shared__ int sidx[64];
    __shared__ float sls[64];
    __shared__ int list[64];
    __shared__ int cnt;
    __shared__ float tile[64][130];
    const int tid = threadIdx.x;
    const int b = blockIdx.x;
    const int m0 = b * 64;
    if (tid == 0) cnt = 0;
    __syncthreads();
    if (tid < 64) {
        const uint32_t wv = cand[m0 + tid];
        sidx[tid] = (int)(wv & 1023u);
        sls[tid] = xnorm[m0 + tid] + sbest[m0 + tid];
        if (wv >> 30) { const int p = atomicAdd(&cnt, 1); list[p] = tid; }
    }
    __syncthreads();
    const int nf = cnt;
    const int w = tid >> 6, lid = tid & 63;
    for (int it = w; it < nf; it += 4) {
        const int row = m0 + list[it];
        const uint32_t wv = cand[row];
        const int j1 = (int)(wv & 1023u), j2 = (int)((wv >> 10) & 1023u), j3 = (int)((wv >> 20) & 1023u);
        const bool nd3 = (wv >> 31) & 1u;
        const int n = row >> 11, t = row & 2047;
        const float* xc = x + (size_t)n * WIDTH * T_DIM + t;
        float xv[8];
#pragma unroll
        for (int e = 0; e < 8; ++e)
            xv[e] = xc[(size_t)(lid * 8 + e) * T_DIM];
        float d1 = 0.f, d2 = 0.f, d3 = 0.f;
        {
            const float* c1 = cb + (size_t)j1 * WIDTH + lid * 8;
            const float* c2 = cb + (size_t)j2 * WIDTH + lid * 8;
            const float* c3 = cb + (size_t)j3 * WIDTH + lid * 8;
            float4 a0 = *(const float4*)c1, a1 = *(const float4*)(c1 + 4);
            d1 = fmaf(xv[0], a0.x, fmaf(xv[1], a0.y, fmaf(xv[2], a0.z, fmaf(xv[3], a0.w,
                 fmaf(xv[4], a1.x, fmaf(xv[5], a1.y, fmaf(xv[6], a1.z, xv[7] * a1.w)))))));
            float4 b0 = *(const float4*)c2, b1v = *(const float4*)(c2 + 4);
            d2 = fmaf(xv[0], b0.x, fmaf(xv[1], b0.y, fmaf(xv[2], b0.z, fmaf(xv[3], b0.w,
                 fmaf(xv[4], b1v.x, fmaf(xv[5], b1v.y, fmaf(xv[6], b1v.z, xv[7] * b1v.w)))))));
            if (nd3) {
                float4 g0 = *(const float4*)c3, g1 = *(const float4*)(c3 + 4);
                d3 = fmaf(xv[0], g0.x, fmaf(xv[1], g0.y, fmaf(xv[2], g0.z, fmaf(xv[3], g0.w,
                     fmaf(xv[4], g1.x, fmaf(xv[5], g1.y, fmaf(xv[6], g1.z, xv[7] * g1.w)))))));
            }
        }
#pragma unroll
        for (int off = 32; off >= 1; off >>= 1) {
            d1 += __shfl_xor(d1, off, 64);
            d2 += __shfl_xor(d2, off, 64);
            d3 += __shfl_xor(d3, off, 64);
        }
        if (lid == 0) {
            int win = j1;
            float qw = fmaf(-2.f, d1, cnorm[j1]);
            const float q2 = fmaf(-2.f, d2, cnorm[j2]);
            if (q2 < qw || (q2 == qw && j2 < win)) { win = j2; qw = q2; }
            if (nd3) {
                const float q3 = fmaf(-2.f, d3, cnorm[j3]);
                if (q3 < qw || (q3 == qw && j3 < win)) { win = j3; qw = q3; }
            }
            sidx[list[it]] = win;
            sls[list[it]] = xnorm[row] + qw;
        }
    }
    __syncthreads();
    if (tid < 64) {
        dout[IDX_OFF + m0 + tid] = (float)sidx[tid];
        atomicAdd(&hist[sidx[tid]], 1);
        float ls = sls[tid];
#pragma unroll
        for (int off = 32; off >= 1; off >>= 1) ls += __shfl_xor(ls, off, 64);
        if (tid == 0) lossPart[b] = ls;
    }
    // scatter: codebook[sidx] -> out [N][W][T] via LDS transpose staging
    const int n = b >> 5;
    const int t0 = (b & 31) * 64;
    const int l = tid & 63;
    for (int wc = 0; wc < 4; ++wc) {
#pragma unroll
        for (int rr = 0; rr < 16; ++rr) {
            const int row = w * 16 + rr;
            const float2 v = *(const float2*)(cb + (size_t)sidx[row] * WIDTH + wc * 128 + l * 2);
            *(float2*)&tile[row][l * 2] = v;
        }
        __syncthreads();
#pragma unroll 8
        for (int wwi = 0; wwi < 32; ++wwi) {
            const int ww = wc * 128 + w * 32 + wwi;
            dout[((size_t)n * WIDTH + ww) * T_DIM + t0 + l] = tile[l][w * 32 + wwi];
        }
        __syncthreads();
    }
}

// perplexity from hist + commit loss from 1024 block partials
__global__ __launch_bounds__(1024) void k_fin(
    const int* __restrict__ hist, const float* __restrict__ lossPart,
    float* __restrict__ dout) {
    const int tid = threadIdx.x;
    const float p = (float)hist[tid] * (1.0f / (float)M_ROWS);
    float e = p * logf(p + 1e-7f);
    float ls = lossPart[tid];
#pragma unroll
    for (int off = 32; off >= 1; off >>= 1) {
        e += __shfl_xor(e, off, 64);
        ls += __shfl_xor(ls, off, 64);
    }
    __shared__ float se[16], sl[16];
    if ((tid & 63) == 0) { se[tid >> 6] = e; sl[tid >> 6] = ls; }
    __syncthreads();
    if (tid == 0) {
        float E = 0.f, L = 0.f;
#pragma unroll
        for (int i = 0; i < 16; ++i) { E += se[i]; L += sl[i]; }
        dout[LOSS_OFF] = L / (float)OUT_ELEMS;
        dout[PERP_OFF] = expf(-E);
    }
}

extern "C" void kernel_launch(void* const* d_in, const int* in_sizes, int n_in,
                              void* d_out, int out_size, void* d_ws, size_t ws_size,
                              hipStream_t stream) {
    const float* x = (const float*)d_in[0];
    const float* cb = (const float*)d_in[1];
    float* dout = (float*)d_out;
    uint8_t* w = (uint8_t*)d_ws;

    unsigned short* cbh = (unsigned short*)w;                        // 1 MB
    float* cnorm   = (float*)(w + (1u << 20));                       // 4 KB
    int*   hist    = (int*)(w + (1u << 20) + 4096);                  // 4 KB
    uint32_t* cand = (uint32_t*)(w + (1u << 20) + 8192);             // 256 KB
    float* sbest   = (float*)(w + (1u << 20) + 8192 + 262144);       // 256 KB
    float* xnorm   = (float*)(w + (1u << 20) + 8192 + 2 * 262144);   // 256 KB
    float* lossPart= (float*)(w + (1u << 20) + 8192 + 3 * 262144);   // 4 KB

    k_prep<<<NB_CODE, 128, 0, stream>>>(cb, cbh, cnorm, hist);
    k_argmin<<<M_ROWS / 128, 256, 0, stream>>>(x, cbh, cnorm, cand, sbest, xnorm);
    k_tail<<<1024, 256, 0, stream>>>(x, cb, cnorm, cand, sbest, xnorm, dout, hist, lossPart);
    k_fin<<<1, 1024, 0, stream>>>(hist, lossPart, dout);
}